// Round 1
// 927.436 us; speedup vs baseline: 1.0107x; 1.0107x over previous
//
#include <hip/hip_runtime.h>

// forward_warp bilinear scatter-add, LDS-privatized by destination tile.
// im0: [B,C,H,W] fp32, flow: [B,H,W,2] fp32 (dx,dy), out: [B,C,H,W] fp32
// B=8, C=16, H=512, W=512
//
// v2 (latency restructure): records are register-resident (no s_meta/s_wts),
// Phase B is channel-blocked (8 planes per pass -> 8 independent loads per
// record, 2 passes instead of 16). Same math as the verified v1.

#define BB 8
#define CC 16
#define HH 512
#define WW 512
#define TIL 32             // dest tile edge
#define RAD 4              // halo radius; main path requires f in [-RAD, RAD)
#define REG (TIL + 2*RAD)  // 40
#define NSRC (REG*REG)     // 1600
#define NTHR 256
#define MAXREC ((NSRC + NTHR - 1) / NTHR)  // 7
#define CB 8               // channels per pass (LDS accumulator planes)
#define NPASS (CC / CB)    // 2

__global__ __launch_bounds__(NTHR) void fwarp_tile(
    const float* __restrict__ im0,
    const float* __restrict__ flow,
    float* __restrict__ out)
{
    __shared__ float s_acc[CB * TIL * TIL];   // 32 KB

    const int tid  = threadIdx.x;
    const int tile = blockIdx.x;              // 8 * 16 * 16 = 2048
    const int tcx = tile & 15;
    const int tcy = (tile >> 4) & 15;
    const int b   = tile >> 8;
    const int w0  = tcx * TIL;
    const int h0  = tcy * TIL;

    const float2* flow2 = (const float2*)flow + ((size_t)b << 18);

    // ---- Phase A: per-thread records, held in registers (unrolled -> no scratch)
    float4 rw[MAXREC];     // corner weights (nw, ne, sw, se); all-zero = dead
    int    rbase[MAXREC];  // ly*TIL + lx (may be negative; only used w/ nonzero w)
    int    rspat[MAXREC];  // (sy<<9) + sx ; 0 for dead records (safe load addr)

#pragma unroll
    for (int r = 0; r < MAXREC; ++r) {
        rw[r] = make_float4(0.f, 0.f, 0.f, 0.f);
        rbase[r] = 0;
        rspat[r] = 0;
        const int i = tid + r * NTHR;
        if (i < NSRC) {
            const int ry = i / REG;
            const int rx = i - ry * REG;
            const int sy = h0 - RAD + ry;
            const int sx = w0 - RAD + rx;
            const bool inimg = (sx >= 0) & (sx < WW) & (sy >= 0) & (sy < HH);

            float fxv = 0.0f, fyv = 0.0f;
            if (inimg) {
                const float2 f = flow2[(sy << 9) + sx];
                fxv = f.x; fyv = f.y;
            }
            const float x = (float)sx + fxv;
            const float y = (float)sy + fyv;
            const float x0f = floorf(x);
            const float y0f = floorf(y);
            const int x0 = (int)x0f;
            const int y0 = (int)y0f;

            const bool inrange = (fxv >= -(float)RAD) & (fxv < (float)RAD) &
                                 (fyv >= -(float)RAD) & (fyv < (float)RAD);
            const bool valid = inimg && inrange &&
                               (x0 >= 0) && (x0 <= WW - 2) && (y0 >= 0) && (y0 <= HH - 2);

            const float fx = x - x0f;
            const float fy = y - y0f;
            const int lx = x0 - w0;
            const int ly = y0 - h0;

            const bool okW = (lx >= 0) & (lx < TIL);
            const bool okE = (lx + 1 >= 0) & (lx + 1 < TIL);
            const bool okN = (ly >= 0) & (ly < TIL);
            const bool okS = (ly + 1 >= 0) & (ly + 1 < TIL);

            float4 w4;
            w4.x = (valid && okN && okW) ? (1.0f - fx) * (1.0f - fy) : 0.0f;
            w4.y = (valid && okN && okE) ? fx * (1.0f - fy)          : 0.0f;
            w4.z = (valid && okS && okW) ? (1.0f - fx) * fy          : 0.0f;
            w4.w = (valid && okS && okE) ? fx * fy                   : 0.0f;

            const bool any = (w4.x != 0.0f) | (w4.y != 0.0f) |
                             (w4.z != 0.0f) | (w4.w != 0.0f);
            if (any) {
                rw[r]    = w4;
                rbase[r] = ly * TIL + lx;
                rspat[r] = (sy << 9) + sx;
            }
        }
    }

    // ---- Phase B: two channel-blocked passes; 8 independent loads per record
    for (int p = 0; p < NPASS; ++p) {
        for (int j = tid; j < CB * TIL * TIL / 4; j += NTHR)
            ((float4*)s_acc)[j] = make_float4(0.f, 0.f, 0.f, 0.f);
        __syncthreads();

        const float* imp = im0 + (((size_t)(b * CC + p * CB)) << 18);

#pragma unroll
        for (int r = 0; r < MAXREC; ++r) {
            const float4 w4  = rw[r];
            const int   spat = rspat[r];
            const int   base = rbase[r];
            float v[CB];
#pragma unroll
            for (int cc = 0; cc < CB; ++cc)
                v[cc] = imp[((size_t)cc << 18) + spat];   // 8 independent loads

            if (w4.x != 0.0f) {
#pragma unroll
                for (int cc = 0; cc < CB; ++cc)
                    atomicAdd(&s_acc[cc * (TIL * TIL) + base], w4.x * v[cc]);
            }
            if (w4.y != 0.0f) {
#pragma unroll
                for (int cc = 0; cc < CB; ++cc)
                    atomicAdd(&s_acc[cc * (TIL * TIL) + base + 1], w4.y * v[cc]);
            }
            if (w4.z != 0.0f) {
#pragma unroll
                for (int cc = 0; cc < CB; ++cc)
                    atomicAdd(&s_acc[cc * (TIL * TIL) + base + TIL], w4.z * v[cc]);
            }
            if (w4.w != 0.0f) {
#pragma unroll
                for (int cc = 0; cc < CB; ++cc)
                    atomicAdd(&s_acc[cc * (TIL * TIL) + base + TIL + 1], w4.w * v[cc]);
            }
        }
        __syncthreads();

        // coalesced float4 tile stores (w0 multiple of 32 -> 16B aligned)
        float* outp = out + (((size_t)(b * CC + p * CB)) << 18);
        for (int jj = tid; jj < CB * TIL * TIL / 4; jj += NTHR) {
            const int c  = jj >> 8;         // 256 float4 per channel tile
            const int q  = jj & 255;
            const int dy = q >> 3;          // 8 float4 per row
            const int dx = (q & 7) << 2;
            const float4 val = ((const float4*)s_acc)[jj];
            *(float4*)(outp + ((size_t)c << 18) + ((h0 + dy) << 9) + w0 + dx) = val;
        }
        __syncthreads();  // protect s_acc before next pass's zeroing
    }
}

// Exact fallback for sources with flow outside [-RAD, RAD): global atomic
// scatter, stream-ordered AFTER fwarp_tile's non-atomic stores.
// v2: x4 pixels per thread via float4 flow loads.
__global__ __launch_bounds__(256) void fwarp_fallback(
    const float* __restrict__ im0,
    const float* __restrict__ flow,
    float* __restrict__ out)
{
    const int t = blockIdx.x * blockDim.x + threadIdx.x;   // handles 4 pixels
    const int idx0 = t << 2;

    const float4 fA = ((const float4*)flow)[(t << 1)];
    const float4 fB = ((const float4*)flow)[(t << 1) + 1];
    const float pfx[4] = {fA.x, fA.z, fB.x, fB.z};
    const float pfy[4] = {fA.y, fA.w, fB.y, fB.w};

#pragma unroll
    for (int k = 0; k < 4; ++k) {
        const float fxv = pfx[k];
        const float fyv = pfy[k];
        const bool inrange = (fxv >= -(float)RAD) & (fxv < (float)RAD) &
                             (fyv >= -(float)RAD) & (fyv < (float)RAD);
        if (inrange) continue;  // handled by fwarp_tile

        const int idx = idx0 + k;
        const int w = idx & (WW - 1);
        const int h = (idx >> 9) & (HH - 1);
        const int b = idx >> 18;

        const float x = (float)w + fxv;
        const float y = (float)h + fyv;
        const float x0f = floorf(x);
        const float y0f = floorf(y);
        const int x0 = (int)x0f;
        const int y0 = (int)y0f;
        if (x0 < 0 || x0 > WW - 2 || y0 < 0 || y0 > HH - 2) continue;

        const float fx = x - x0f;
        const float fy = y - y0f;
        const float wnw = (1.0f - fx) * (1.0f - fy);
        const float wne = fx * (1.0f - fy);
        const float wsw = (1.0f - fx) * fy;
        const float wse = fx * fy;

        const size_t plane = (size_t)HH * WW;
        const float* srcb = im0 + (size_t)b * CC * plane + (size_t)h * WW + w;
        float* dstb       = out + (size_t)b * CC * plane;
        const int o = y0 * WW + x0;

#pragma unroll
        for (int c = 0; c < CC; ++c) {
            const float v = srcb[c * plane];
            float* dc = dstb + c * plane;
            atomicAdd(dc + o,          v * wnw);
            atomicAdd(dc + o + 1,      v * wne);
            atomicAdd(dc + o + WW,     v * wsw);
            atomicAdd(dc + o + WW + 1, v * wse);
        }
    }
}

extern "C" void kernel_launch(void* const* d_in, const int* in_sizes, int n_in,
                              void* d_out, int out_size, void* d_ws, size_t ws_size,
                              hipStream_t stream) {
    const float* im0  = (const float*)d_in[0];
    const float* flow = (const float*)d_in[1];
    float* out = (float*)d_out;

    // Main kernel writes every output element exactly once -> no memset needed.
    const int n_tiles = BB * (HH / TIL) * (WW / TIL);  // 2048
    fwarp_tile<<<n_tiles, NTHR, 0, stream>>>(im0, flow, out);

    // Rare long-range sources: exact global-atomic scatter, ordered after.
    const int n_pix = BB * HH * WW;                    // 2M; 4 px/thread
    fwarp_fallback<<<n_pix / (256 * 4), 256, 0, stream>>>(im0, flow, out);
}

// Round 2
// 443.711 us; speedup vs baseline: 2.1125x; 2.0902x over previous
//
#include <hip/hip_runtime.h>

// forward_warp bilinear scatter-add, v3: CSR-binned gather (atomic-free accumulation).
// im0: [B,C,H,W] fp32, flow: [B,H,W,2] fp32 (dx,dy), out: [B,C,H,W] fp32
// B=8, C=16, H=512, W=512
//
// Theory: v1/v2 both bottomed at ~700us with all pipes idle; the invariant was
// ~102K LDS fp32 lane-atomics per block (~0.7 RMW/cy/CU effective). v3 removes
// per-(corner,channel) float atomics entirely:
//   Phase A: count + prefix-scan + fill a CSR list of (source, corner) entries
//            per dest pixel (only u32 increments, 8x fewer lane-atomics).
//   Phase B: each thread gathers its 4 dest pixels' contributions, recomputes
//            weights from LDS-staged flow (identical fp32 math), accumulates
//            16 channels in REGISTERS, stores coalesced.
// Sources with |flow| >= RAD handled exactly by the global-atomic fallback.

#define BB 8
#define CC 16
#define HH 512
#define WW 512
#define TIL 32             // dest tile edge
#define RAD 4              // halo radius; main path requires f in [-RAD, RAD)
#define REG (TIL + 2*RAD)  // 40
#define NSRC (REG*REG)     // 1600
#define NTHR 256
#define NENT (NSRC * 4)    // hard bound on CSR entries: 6400

// Per-source decode, used identically in count and fill passes (must match!).
#define SRC_DECODE(i) \
    const int ry = (i) / REG; const int rx = (i) - ry * REG;                     \
    const int sy = h0 - RAD + ry; const int sx = w0 - RAD + rx;                  \
    const bool inimg = (sx >= 0) & (sx < WW) & (sy >= 0) & (sy < HH);            \
    const float2 f = s_flow[i];                                                  \
    const float x = (float)sx + f.x; const float y = (float)sy + f.y;            \
    const float x0f = floorf(x);     const float y0f = floorf(y);                \
    const int x0 = (int)x0f;         const int y0 = (int)y0f;                    \
    const bool inrange = (f.x >= -(float)RAD) & (f.x < (float)RAD) &             \
                         (f.y >= -(float)RAD) & (f.y < (float)RAD);              \
    const bool valid = inimg && inrange &&                                       \
                       (x0 >= 0) && (x0 <= WW - 2) && (y0 >= 0) && (y0 <= HH-2); \
    const float fx = x - x0f; const float fy = y - y0f;                          \
    const int lx = x0 - w0;   const int ly = y0 - h0;                            \
    const bool okW = (lx >= 0)  & (lx < TIL);                                    \
    const bool okE = (lx >= -1) & (lx < TIL - 1);                                \
    const bool okN = (ly >= 0)  & (ly < TIL);                                    \
    const bool okS = (ly >= -1) & (ly < TIL - 1);                                \
    const float wnw = (1.0f-fx)*(1.0f-fy), wne = fx*(1.0f-fy);                   \
    const float wsw = (1.0f-fx)*fy,        wse = fx*fy;                          \
    const bool k0 = valid && okN && okW && (wnw != 0.0f);                        \
    const bool k1 = valid && okN && okE && (wne != 0.0f);                        \
    const bool k2 = valid && okS && okW && (wsw != 0.0f);                        \
    const bool k3 = valid && okS && okE && (wse != 0.0f);                        \
    const int p0 = ly * TIL + lx, p1 = p0 + 1, p2 = p0 + TIL, p3 = p0 + TIL + 1;

__global__ __launch_bounds__(NTHR) void fwarp_tile(
    const float* __restrict__ im0,
    const float* __restrict__ flow,
    float* __restrict__ out)
{
    __shared__ float2   s_flow[NSRC];        // 12.8 KB staged flow region
    __shared__ unsigned s_off[TIL * TIL];    // 4 KB  CSR row starts
    __shared__ unsigned s_cur[TIL * TIL];    // 4 KB  counts -> cursors -> row ends
    __shared__ unsigned s_ent[NENT];         // 25.6 KB entries: (src_idx<<2)|corner
    __shared__ unsigned s_wtot[4];

    const int tid  = threadIdx.x;
    const int tile = blockIdx.x;             // 8 * 16 * 16 = 2048
    const int tcx = tile & 15;
    const int tcy = (tile >> 4) & 15;
    const int b   = tile >> 8;
    const int w0  = tcx * TIL;
    const int h0  = tcy * TIL;

    const float2* flow2 = (const float2*)flow + ((size_t)b << 18);

    // ---- Phase 0: stage flow region (coalesced) + zero counts ----
    for (int i = tid; i < NSRC; i += NTHR) {
        const int ry = i / REG;
        const int rx = i - ry * REG;
        const int sy = h0 - RAD + ry;
        const int sx = w0 - RAD + rx;
        float2 f = make_float2(0.0f, 0.0f);
        if ((sx >= 0) & (sx < WW) & (sy >= 0) & (sy < HH))
            f = flow2[(sy << 9) + sx];
        s_flow[i] = f;
    }
    for (int j = tid; j < TIL * TIL; j += NTHR) s_cur[j] = 0u;
    __syncthreads();

    // ---- Phase 1: count contributions per dest pixel ----
    for (int i = tid; i < NSRC; i += NTHR) {
        SRC_DECODE(i);
        if (k0) atomicAdd(&s_cur[p0], 1u);
        if (k1) atomicAdd(&s_cur[p1], 1u);
        if (k2) atomicAdd(&s_cur[p2], 1u);
        if (k3) atomicAdd(&s_cur[p3], 1u);
    }
    __syncthreads();

    // ---- Phase 2: exclusive prefix scan (1024 counts, 4 per thread) ----
    {
        const int lane = tid & 63;
        const int wv   = tid >> 6;
        const unsigned ca = s_cur[tid * 4 + 0];
        const unsigned cb = s_cur[tid * 4 + 1];
        const unsigned cc = s_cur[tid * 4 + 2];
        const unsigned cd = s_cur[tid * 4 + 3];
        const unsigned mysum = ca + cb + cc + cd;
        unsigned inc = mysum;
#pragma unroll
        for (int d = 1; d < 64; d <<= 1) {
            const unsigned u = __shfl_up(inc, d);
            if (lane >= d) inc += u;
        }
        if (lane == 63) s_wtot[wv] = inc;
        __syncthreads();
        unsigned wpre = 0;
#pragma unroll
        for (int w = 0; w < 3; ++w) if (wv > w) wpre += s_wtot[w];
        const unsigned o0 = wpre + inc - mysum;
        const unsigned o1 = o0 + ca;
        const unsigned o2 = o1 + cb;
        const unsigned o3 = o2 + cc;
        s_off[tid * 4 + 0] = o0;  s_cur[tid * 4 + 0] = o0;
        s_off[tid * 4 + 1] = o1;  s_cur[tid * 4 + 1] = o1;
        s_off[tid * 4 + 2] = o2;  s_cur[tid * 4 + 2] = o2;
        s_off[tid * 4 + 3] = o3;  s_cur[tid * 4 + 3] = o3;
    }
    __syncthreads();

    // ---- Phase 3: fill CSR entries ----
    for (int i = tid; i < NSRC; i += NTHR) {
        SRC_DECODE(i);
        if (k0) { const unsigned s = atomicAdd(&s_cur[p0], 1u); s_ent[s] = ((unsigned)i << 2) | 0u; }
        if (k1) { const unsigned s = atomicAdd(&s_cur[p1], 1u); s_ent[s] = ((unsigned)i << 2) | 1u; }
        if (k2) { const unsigned s = atomicAdd(&s_cur[p2], 1u); s_ent[s] = ((unsigned)i << 2) | 2u; }
        if (k3) { const unsigned s = atomicAdd(&s_cur[p3], 1u); s_ent[s] = ((unsigned)i << 2) | 3u; }
    }
    __syncthreads();
    // s_cur[p] now == row end for pixel p.

    // ---- Phase 4: gather — 4 dest pixels/thread, 16 channels in registers ----
    const float* imb = im0 + ((size_t)(b * CC) << 18);
    float* outb      = out + ((size_t)(b * CC) << 18);

#pragma unroll
    for (int k = 0; k < 4; ++k) {
        const int p   = tid + k * NTHR;          // dest pixel index in tile
        const int beg = (int)s_off[p];
        const int end = (int)s_cur[p];

        float acc[CC];
#pragma unroll
        for (int c = 0; c < CC; ++c) acc[c] = 0.0f;

        for (int j = beg; j < end; ++j) {
            const unsigned e = s_ent[j];
            const int corner = (int)(e & 3u);
            const int sidx   = (int)(e >> 2);
            const int ry = sidx / REG;
            const int rx = sidx - ry * REG;
            const float2 f = s_flow[sidx];
            const int sy = h0 - RAD + ry;
            const int sx = w0 - RAD + rx;
            const float x = (float)sx + f.x;
            const float y = (float)sy + f.y;
            const float x0f = floorf(x);
            const float y0f = floorf(y);
            const float fx = x - x0f;
            const float fy = y - y0f;
            const float wx = (corner & 1) ? fx : 1.0f - fx;
            const float wy = (corner & 2) ? fy : 1.0f - fy;
            const float w  = wx * wy;

            const float* ip = imb + ((sy << 9) + sx);
#pragma unroll
            for (int c = 0; c < CC; ++c)
                acc[c] += w * ip[(size_t)c << 18];   // 16 independent loads
        }

        // coalesced stores: lanes -> consecutive dx within a row
        const int dy = p >> 5;
        const int dx = p & 31;
        float* op = outb + (((h0 + dy) << 9) + (w0 + dx));
#pragma unroll
        for (int c = 0; c < CC; ++c)
            op[(size_t)c << 18] = acc[c];
    }
}

// Exact fallback for sources with flow outside [-RAD, RAD): global atomic
// scatter, stream-ordered AFTER fwarp_tile's non-atomic stores.
__global__ __launch_bounds__(256) void fwarp_fallback(
    const float* __restrict__ im0,
    const float* __restrict__ flow,
    float* __restrict__ out)
{
    const int t = blockIdx.x * blockDim.x + threadIdx.x;   // handles 4 pixels
    const int idx0 = t << 2;

    const float4 fA = ((const float4*)flow)[(t << 1)];
    const float4 fB = ((const float4*)flow)[(t << 1) + 1];
    const float pfx[4] = {fA.x, fA.z, fB.x, fB.z};
    const float pfy[4] = {fA.y, fA.w, fB.y, fB.w};

#pragma unroll
    for (int k = 0; k < 4; ++k) {
        const float fxv = pfx[k];
        const float fyv = pfy[k];
        const bool inrange = (fxv >= -(float)RAD) & (fxv < (float)RAD) &
                             (fyv >= -(float)RAD) & (fyv < (float)RAD);
        if (inrange) continue;  // handled by fwarp_tile

        const int idx = idx0 + k;
        const int w = idx & (WW - 1);
        const int h = (idx >> 9) & (HH - 1);
        const int b = idx >> 18;

        const float x = (float)w + fxv;
        const float y = (float)h + fyv;
        const float x0f = floorf(x);
        const float y0f = floorf(y);
        const int x0 = (int)x0f;
        const int y0 = (int)y0f;
        if (x0 < 0 || x0 > WW - 2 || y0 < 0 || y0 > HH - 2) continue;

        const float fx = x - x0f;
        const float fy = y - y0f;
        const float wnw = (1.0f - fx) * (1.0f - fy);
        const float wne = fx * (1.0f - fy);
        const float wsw = (1.0f - fx) * fy;
        const float wse = fx * fy;

        const size_t plane = (size_t)HH * WW;
        const float* srcb = im0 + (size_t)b * CC * plane + (size_t)h * WW + w;
        float* dstb       = out + (size_t)b * CC * plane;
        const int o = y0 * WW + x0;

#pragma unroll
        for (int c = 0; c < CC; ++c) {
            const float v = srcb[c * plane];
            float* dc = dstb + c * plane;
            atomicAdd(dc + o,          v * wnw);
            atomicAdd(dc + o + 1,      v * wne);
            atomicAdd(dc + o + WW,     v * wsw);
            atomicAdd(dc + o + WW + 1, v * wse);
        }
    }
}

extern "C" void kernel_launch(void* const* d_in, const int* in_sizes, int n_in,
                              void* d_out, int out_size, void* d_ws, size_t ws_size,
                              hipStream_t stream) {
    const float* im0  = (const float*)d_in[0];
    const float* flow = (const float*)d_in[1];
    float* out = (float*)d_out;

    // Main kernel writes every output element exactly once -> no memset needed.
    const int n_tiles = BB * (HH / TIL) * (WW / TIL);  // 2048
    fwarp_tile<<<n_tiles, NTHR, 0, stream>>>(im0, flow, out);

    // Rare long-range sources: exact global-atomic scatter, ordered after.
    const int n_pix = BB * HH * WW;                    // 2M; 4 px/thread
    fwarp_fallback<<<n_pix / (256 * 4), 256, 0, stream>>>(im0, flow, out);
}

// Round 3
// 354.644 us; speedup vs baseline: 2.6430x; 1.2511x over previous
//
#include <hip/hip_runtime.h>

// forward_warp bilinear scatter-add, v4: CSR gather with LDS-staged image.
// im0: [B,C,H,W] fp32, flow: [B,H,W,2] fp32 (dx,dy), out: [B,C,H,W] fp32
// B=8, C=16, H=512, W=512
//
// v3 post-mortem: phase-4's 16 scattered per-lane GLOBAL loads per entry were
// the wall (~1856 scattered wave-loads/block x ~35cy L1 fan-out = 520K cyc/CU).
// v4: stage the 40x40 source region in LDS channel-interleaved (float4 = 4
// channels per group, 4 groups), so one ds_read_b128 replaces 16 L1-scattered
// loads. Weights precomputed into the CSR (u16 spat + f32 w). Decode runs once
// into registers (shared by count+fill). 512 threads -> 16 waves/CU.

#define BB 8
#define CC 16
#define HH 512
#define WW 512
#define TIL 32             // dest tile edge
#define RAD 4              // halo radius; main path requires f in [-RAD, RAD)
#define REG (TIL + 2*RAD)  // 40
#define NSRC (REG*REG)     // 1600
#define NTHR 512
#define NREC ((NSRC + NTHR - 1) / NTHR)  // 4 records per thread
#define NENT (NSRC * 4)    // hard bound on CSR entries: 6400
#define CB 4               // channels per group (float4-interleaved LDS image)
#define NGRP (CC / CB)     // 4

__global__ __launch_bounds__(NTHR, 4) void fwarp_tile(
    const float* __restrict__ im0,
    const float* __restrict__ flow,
    float* __restrict__ out)
{
    __shared__ unsigned short s_ent16[NENT]; // 12.8 KB  entry -> source spat
    __shared__ float          s_wt[NENT];    // 25.6 KB  entry -> bilinear weight
    __shared__ unsigned       s_off[TIL*TIL];// 4 KB     CSR row starts
    __shared__ unsigned       s_cur[TIL*TIL];// 4 KB     counts -> cursors -> ends
    __shared__ float4         s_img[NSRC];   // 25.6 KB  4-channel-interleaved img
    __shared__ unsigned       s_wtot[8];

    const int tid  = threadIdx.x;
    const int tile = blockIdx.x;             // 8 * 16 * 16 = 2048
    const int tcx = tile & 15;
    const int tcy = (tile >> 4) & 15;
    const int b   = tile >> 8;
    const int w0  = tcx * TIL;
    const int h0  = tcy * TIL;

    const float2* flow2 = (const float2*)flow + ((size_t)b << 18);

    // ---- Phase A: decode each source ONCE into registers ----
    float4 rw[NREC];       // corner weights (nw, ne, sw, se)
    int    rp0[NREC];      // ly*TIL + lx (NW corner pixel index, may be <0)
    int    rk[NREC];       // corner validity mask

    for (int j = tid; j < TIL * TIL; j += NTHR) s_cur[j] = 0u;

#pragma unroll
    for (int r = 0; r < NREC; ++r) {
        rk[r] = 0; rp0[r] = 0;
        rw[r] = make_float4(0.f, 0.f, 0.f, 0.f);
        const int i = tid + r * NTHR;
        if (i < NSRC) {
            const int ry = i / REG;
            const int rx = i - ry * REG;
            const int sy = h0 - RAD + ry;
            const int sx = w0 - RAD + rx;
            const bool inimg = (sx >= 0) & (sx < WW) & (sy >= 0) & (sy < HH);

            float fxv = 0.0f, fyv = 0.0f;
            if (inimg) {
                const float2 f = flow2[(sy << 9) + sx];
                fxv = f.x; fyv = f.y;
            }
            const float x = (float)sx + fxv;
            const float y = (float)sy + fyv;
            const float x0f = floorf(x);
            const float y0f = floorf(y);
            const int x0 = (int)x0f;
            const int y0 = (int)y0f;

            const bool inrange = (fxv >= -(float)RAD) & (fxv < (float)RAD) &
                                 (fyv >= -(float)RAD) & (fyv < (float)RAD);
            const bool valid = inimg && inrange &&
                               (x0 >= 0) && (x0 <= WW - 2) && (y0 >= 0) && (y0 <= HH - 2);

            const float fx = x - x0f;
            const float fy = y - y0f;
            const int lx = x0 - w0;
            const int ly = y0 - h0;

            const bool okW = (lx >= 0)  & (lx < TIL);
            const bool okE = (lx >= -1) & (lx < TIL - 1);
            const bool okN = (ly >= 0)  & (ly < TIL);
            const bool okS = (ly >= -1) & (ly < TIL - 1);

            const float wnw = (1.0f - fx) * (1.0f - fy);
            const float wne = fx * (1.0f - fy);
            const float wsw = (1.0f - fx) * fy;
            const float wse = fx * fy;

            int m = 0;
            if (valid && okN && okW && (wnw != 0.0f)) m |= 1;
            if (valid && okN && okE && (wne != 0.0f)) m |= 2;
            if (valid && okS && okW && (wsw != 0.0f)) m |= 4;
            if (valid && okS && okE && (wse != 0.0f)) m |= 8;

            rk[r]  = m;
            rp0[r] = ly * TIL + lx;
            rw[r]  = make_float4(wnw, wne, wsw, wse);
        }
    }
    __syncthreads();

    // ---- Phase 1: count contributions per dest pixel ----
#pragma unroll
    for (int r = 0; r < NREC; ++r) {
        const int m = rk[r];
        const int p0 = rp0[r];
        if (m & 1) atomicAdd(&s_cur[p0], 1u);
        if (m & 2) atomicAdd(&s_cur[p0 + 1], 1u);
        if (m & 4) atomicAdd(&s_cur[p0 + TIL], 1u);
        if (m & 8) atomicAdd(&s_cur[p0 + TIL + 1], 1u);
    }
    __syncthreads();

    // ---- Phase 2: exclusive prefix scan (1024 counts, 2 per thread) ----
    {
        const int lane = tid & 63;
        const int wv   = tid >> 6;             // 0..7
        const unsigned ca = s_cur[tid * 2 + 0];
        const unsigned cb = s_cur[tid * 2 + 1];
        const unsigned mysum = ca + cb;
        unsigned inc = mysum;
#pragma unroll
        for (int d = 1; d < 64; d <<= 1) {
            const unsigned u = __shfl_up(inc, d);
            if (lane >= d) inc += u;
        }
        if (lane == 63) s_wtot[wv] = inc;
        __syncthreads();
        unsigned wpre = 0;
#pragma unroll
        for (int w = 0; w < 7; ++w) if (wv > w) wpre += s_wtot[w];
        const unsigned o0 = wpre + inc - mysum;
        const unsigned o1 = o0 + ca;
        s_off[tid * 2 + 0] = o0;  s_cur[tid * 2 + 0] = o0;
        s_off[tid * 2 + 1] = o1;  s_cur[tid * 2 + 1] = o1;
    }
    __syncthreads();

    // ---- Phase 3: fill CSR entries (spat u16 + precomputed weight f32) ----
#pragma unroll
    for (int r = 0; r < NREC; ++r) {
        const int i = tid + r * NTHR;          // source spat (local index)
        const int m = rk[r];
        const int p0 = rp0[r];
        const float4 w4 = rw[r];
        if (m & 1) { const unsigned s = atomicAdd(&s_cur[p0],           1u); s_ent16[s] = (unsigned short)i; s_wt[s] = w4.x; }
        if (m & 2) { const unsigned s = atomicAdd(&s_cur[p0 + 1],       1u); s_ent16[s] = (unsigned short)i; s_wt[s] = w4.y; }
        if (m & 4) { const unsigned s = atomicAdd(&s_cur[p0 + TIL],     1u); s_ent16[s] = (unsigned short)i; s_wt[s] = w4.z; }
        if (m & 8) { const unsigned s = atomicAdd(&s_cur[p0 + TIL + 1], 1u); s_ent16[s] = (unsigned short)i; s_wt[s] = w4.w; }
    }
    __syncthreads();
    // s_cur[p] now == row end for pixel p.

    // cache row bounds in registers (read-only through all groups)
    int rbeg[2], rend[2];
#pragma unroll
    for (int k = 0; k < 2; ++k) {
        const int p = tid + k * NTHR;
        rbeg[k] = (int)s_off[p];
        rend[k] = (int)s_cur[p];
    }

    const float* imb = im0 + ((size_t)(b * CC) << 18);
    float* outb      = out + ((size_t)(b * CC) << 18);

    // ---- Phase 4: per channel-group: stage LDS image (float4), gather ----
    for (int g = 0; g < NGRP; ++g) {
        const float* imgp = imb + ((size_t)(g * CB) << 18);

        // stage: s_img[i] = {c0, c1, c2, c3} at source pixel i (coalesced)
#pragma unroll
        for (int r = 0; r < NREC; ++r) {
            const int i = tid + r * NTHR;
            if (i < NSRC) {
                const int ry = i / REG;
                const int rx = i - ry * REG;
                const int sy = h0 - RAD + ry;
                const int sx = w0 - RAD + rx;
                const bool inimg = (sx >= 0) & (sx < WW) & (sy >= 0) & (sy < HH);
                const int gi = inimg ? ((sy << 9) + sx) : 0;  // safe addr; dead if OOB
                float4 v;
                v.x = imgp[gi];
                v.y = imgp[((size_t)1 << 18) + gi];
                v.z = imgp[((size_t)2 << 18) + gi];
                v.w = imgp[((size_t)3 << 18) + gi];
                s_img[i] = v;
            }
        }
        __syncthreads();

        // gather: 2 dest pixels/thread, 4 channels in registers
#pragma unroll
        for (int k = 0; k < 2; ++k) {
            const int p   = tid + k * NTHR;
            const int beg = rbeg[k];
            const int end = rend[k];

            float a0 = 0.f, a1 = 0.f, a2 = 0.f, a3 = 0.f;
            for (int j = beg; j < end; ++j) {
                const int   sp = (int)s_ent16[j];
                const float w  = s_wt[j];
                const float4 v = s_img[sp];
                a0 = fmaf(w, v.x, a0);
                a1 = fmaf(w, v.y, a1);
                a2 = fmaf(w, v.z, a2);
                a3 = fmaf(w, v.w, a3);
            }

            const int dy = p >> 5;
            const int dx = p & 31;
            float* op = outb + ((size_t)(g * CB) << 18) + ((h0 + dy) << 9) + (w0 + dx);
            op[0]                 = a0;
            op[(size_t)1 << 18]   = a1;
            op[(size_t)2 << 18]   = a2;
            op[(size_t)3 << 18]   = a3;
        }
        __syncthreads();  // protect s_img before next group's staging
    }
}

// Exact fallback for sources with flow outside [-RAD, RAD): global atomic
// scatter, stream-ordered AFTER fwarp_tile's non-atomic stores.
__global__ __launch_bounds__(256) void fwarp_fallback(
    const float* __restrict__ im0,
    const float* __restrict__ flow,
    float* __restrict__ out)
{
    const int t = blockIdx.x * blockDim.x + threadIdx.x;   // handles 4 pixels
    const int idx0 = t << 2;

    const float4 fA = ((const float4*)flow)[(t << 1)];
    const float4 fB = ((const float4*)flow)[(t << 1) + 1];
    const float pfx[4] = {fA.x, fA.z, fB.x, fB.z};
    const float pfy[4] = {fA.y, fA.w, fB.y, fB.w};

#pragma unroll
    for (int k = 0; k < 4; ++k) {
        const float fxv = pfx[k];
        const float fyv = pfy[k];
        const bool inrange = (fxv >= -(float)RAD) & (fxv < (float)RAD) &
                             (fyv >= -(float)RAD) & (fyv < (float)RAD);
        if (inrange) continue;  // handled by fwarp_tile

        const int idx = idx0 + k;
        const int w = idx & (WW - 1);
        const int h = (idx >> 9) & (HH - 1);
        const int b = idx >> 18;

        const float x = (float)w + fxv;
        const float y = (float)h + fyv;
        const float x0f = floorf(x);
        const float y0f = floorf(y);
        const int x0 = (int)x0f;
        const int y0 = (int)y0f;
        if (x0 < 0 || x0 > WW - 2 || y0 < 0 || y0 > HH - 2) continue;

        const float fx = x - x0f;
        const float fy = y - y0f;
        const float wnw = (1.0f - fx) * (1.0f - fy);
        const float wne = fx * (1.0f - fy);
        const float wsw = (1.0f - fx) * fy;
        const float wse = fx * fy;

        const size_t plane = (size_t)HH * WW;
        const float* srcb = im0 + (size_t)b * CC * plane + (size_t)h * WW + w;
        float* dstb       = out + (size_t)b * CC * plane;
        const int o = y0 * WW + x0;

#pragma unroll
        for (int c = 0; c < CC; ++c) {
            const float v = srcb[c * plane];
            float* dc = dstb + c * plane;
            atomicAdd(dc + o,          v * wnw);
            atomicAdd(dc + o + 1,      v * wne);
            atomicAdd(dc + o + WW,     v * wsw);
            atomicAdd(dc + o + WW + 1, v * wse);
        }
    }
}

extern "C" void kernel_launch(void* const* d_in, const int* in_sizes, int n_in,
                              void* d_out, int out_size, void* d_ws, size_t ws_size,
                              hipStream_t stream) {
    const float* im0  = (const float*)d_in[0];
    const float* flow = (const float*)d_in[1];
    float* out = (float*)d_out;

    // Main kernel writes every output element exactly once -> no memset needed.
    const int n_tiles = BB * (HH / TIL) * (WW / TIL);  // 2048
    fwarp_tile<<<n_tiles, NTHR, 0, stream>>>(im0, flow, out);

    // Rare long-range sources: exact global-atomic scatter, ordered after.
    const int n_pix = BB * HH * WW;                    // 2M; 4 px/thread
    fwarp_fallback<<<n_pix / (256 * 4), 256, 0, stream>>>(im0, flow, out);
}

// Round 4
// 326.975 us; speedup vs baseline: 2.8666x; 1.0846x over previous
//
#include <hip/hip_runtime.h>

// forward_warp bilinear scatter-add, v5: 3-blocks/CU CSR gather, async-staged.
// im0: [B,C,H,W] fp32, flow: [B,H,W,2] fp32 (dx,dy), out: [B,C,H,W] fp32
// B=8, C=16, H=512, W=512
//
// v4 post-mortem: 130us with nothing saturated (HBM 33%, VALU 22%, occ 38%)
// -> structural bubbles: 2 blocks/CU can't cover 21 barrier drains, and the
// stage->barrier->gather chain serializes HBM latency with LDS work.
// v5: (1) LDS diet to 42.5 KB -> 3 blocks/CU (packed u32 CSR entries:
// spat<<16 | u16 fixed-point weight; float2 image groups, 8 groups);
// (2) async-stage split: next group's planes loaded into REGISTERS during
// current group's gather, ds_write after the barrier (T14);
// (3) XCD chunk swizzle: each XCD owns one batch image -> halo re-reads hit
// its private L2 (T1).

#define BB 8
#define CC 16
#define HH 512
#define WW 512
#define TIL 32             // dest tile edge
#define RAD 4              // halo radius; main path requires f in [-RAD, RAD)
#define REG (TIL + 2*RAD)  // 40
#define NSRC (REG*REG)     // 1600
#define NTHR 512
#define NREC ((NSRC + NTHR - 1) / NTHR)  // 4 records per thread
#define NENT (NSRC * 4)    // hard bound on CSR entries: 6400
#define CB 2               // channels per group (float2-interleaved LDS image)
#define NGRP (CC / CB)     // 8

__global__ __launch_bounds__(NTHR, 6) void fwarp_tile(
    const float* __restrict__ im0,
    const float* __restrict__ flow,
    float* __restrict__ out)
{
    __shared__ unsigned s_ent[NENT];      // 25.6 KB  entry: spat<<16 | u16 weight
    __shared__ unsigned s_cur[TIL * TIL]; // 4 KB     counts -> row starts -> ends
    __shared__ float2   s_img[NSRC];      // 12.8 KB  2-channel-interleaved image
    __shared__ unsigned s_wtot[8];

    const int tid = threadIdx.x;
    // XCD chunk swizzle: 2048 blocks = 8 XCDs x 256; XCD k owns batch b=k.
    const int bid  = blockIdx.x;
    const int tile = ((bid & 7) << 8) | (bid >> 3);
    const int tcx = tile & 15;
    const int tcy = (tile >> 4) & 15;
    const int b   = tile >> 8;
    const int w0  = tcx * TIL;
    const int h0  = tcy * TIL;

    const float2* flow2 = (const float2*)flow + ((size_t)b << 18);

    // ---- Phase A: decode each source ONCE into registers ----
    float4 rw[NREC];       // corner weights (nw, ne, sw, se)
    int    rp0[NREC];      // ly*TIL + lx (NW corner pixel index, may be <0)
    int    rk[NREC];       // corner validity mask
    int    rgi[NREC];      // global spatial index for staging (0 if OOB)

    for (int j = tid; j < TIL * TIL; j += NTHR) s_cur[j] = 0u;

#pragma unroll
    for (int r = 0; r < NREC; ++r) {
        rk[r] = 0; rp0[r] = 0; rgi[r] = 0;
        rw[r] = make_float4(0.f, 0.f, 0.f, 0.f);
        const int i = tid + r * NTHR;
        if (i < NSRC) {
            const int ry = i / REG;
            const int rx = i - ry * REG;
            const int sy = h0 - RAD + ry;
            const int sx = w0 - RAD + rx;
            const bool inimg = (sx >= 0) & (sx < WW) & (sy >= 0) & (sy < HH);
            rgi[r] = inimg ? ((sy << 9) + sx) : 0;

            float fxv = 0.0f, fyv = 0.0f;
            if (inimg) {
                const float2 f = flow2[(sy << 9) + sx];
                fxv = f.x; fyv = f.y;
            }
            const float x = (float)sx + fxv;
            const float y = (float)sy + fyv;
            const float x0f = floorf(x);
            const float y0f = floorf(y);
            const int x0 = (int)x0f;
            const int y0 = (int)y0f;

            const bool inrange = (fxv >= -(float)RAD) & (fxv < (float)RAD) &
                                 (fyv >= -(float)RAD) & (fyv < (float)RAD);
            const bool valid = inimg && inrange &&
                               (x0 >= 0) && (x0 <= WW - 2) && (y0 >= 0) && (y0 <= HH - 2);

            const float fx = x - x0f;
            const float fy = y - y0f;
            const int lx = x0 - w0;
            const int ly = y0 - h0;

            const bool okW = (lx >= 0)  & (lx < TIL);
            const bool okE = (lx >= -1) & (lx < TIL - 1);
            const bool okN = (ly >= 0)  & (ly < TIL);
            const bool okS = (ly >= -1) & (ly < TIL - 1);

            const float wnw = (1.0f - fx) * (1.0f - fy);
            const float wne = fx * (1.0f - fy);
            const float wsw = (1.0f - fx) * fy;
            const float wse = fx * fy;

            int m = 0;
            if (valid && okN && okW && (wnw != 0.0f)) m |= 1;
            if (valid && okN && okE && (wne != 0.0f)) m |= 2;
            if (valid && okS && okW && (wsw != 0.0f)) m |= 4;
            if (valid && okS && okE && (wse != 0.0f)) m |= 8;

            rk[r]  = m;
            rp0[r] = ly * TIL + lx;
            rw[r]  = make_float4(wnw, wne, wsw, wse);
        }
    }
    __syncthreads();

    // ---- Phase 1: count contributions per dest pixel ----
#pragma unroll
    for (int r = 0; r < NREC; ++r) {
        const int m = rk[r];
        const int p0 = rp0[r];
        if (m & 1) atomicAdd(&s_cur[p0], 1u);
        if (m & 2) atomicAdd(&s_cur[p0 + 1], 1u);
        if (m & 4) atomicAdd(&s_cur[p0 + TIL], 1u);
        if (m & 8) atomicAdd(&s_cur[p0 + TIL + 1], 1u);
    }
    __syncthreads();

    // ---- Phase 2: exclusive prefix scan (1024 counts, 2 per thread) ----
    {
        const int lane = tid & 63;
        const int wv   = tid >> 6;             // 0..7
        const unsigned ca = s_cur[tid * 2 + 0];
        const unsigned cb = s_cur[tid * 2 + 1];
        const unsigned mysum = ca + cb;
        unsigned inc = mysum;
#pragma unroll
        for (int d = 1; d < 64; d <<= 1) {
            const unsigned u = __shfl_up(inc, d);
            if (lane >= d) inc += u;
        }
        if (lane == 63) s_wtot[wv] = inc;
        __syncthreads();
        unsigned wpre = 0;
#pragma unroll
        for (int w = 0; w < 7; ++w) if (wv > w) wpre += s_wtot[w];
        const unsigned o0 = wpre + inc - mysum;
        const unsigned o1 = o0 + ca;
        s_cur[tid * 2 + 0] = o0;
        s_cur[tid * 2 + 1] = o1;
    }
    __syncthreads();

    // capture row starts for our gather pixels BEFORE cursors get bumped
    int rbeg[2], rend[2];
#pragma unroll
    for (int k = 0; k < 2; ++k) rbeg[k] = (int)s_cur[tid + k * NTHR];
    __syncthreads();

    // ---- Phase 3: fill CSR entries (spat<<16 | u16 fixed-point weight) ----
#pragma unroll
    for (int r = 0; r < NREC; ++r) {
        const int i = tid + r * NTHR;          // source spat (local index)
        const int m = rk[r];
        const int p0 = rp0[r];
        const float4 w4 = rw[r];
        if (m & 1) { const unsigned s = atomicAdd(&s_cur[p0],           1u);
                     s_ent[s] = ((unsigned)i << 16) | (unsigned)(w4.x * 65535.0f + 0.5f); }
        if (m & 2) { const unsigned s = atomicAdd(&s_cur[p0 + 1],       1u);
                     s_ent[s] = ((unsigned)i << 16) | (unsigned)(w4.y * 65535.0f + 0.5f); }
        if (m & 4) { const unsigned s = atomicAdd(&s_cur[p0 + TIL],     1u);
                     s_ent[s] = ((unsigned)i << 16) | (unsigned)(w4.z * 65535.0f + 0.5f); }
        if (m & 8) { const unsigned s = atomicAdd(&s_cur[p0 + TIL + 1], 1u);
                     s_ent[s] = ((unsigned)i << 16) | (unsigned)(w4.w * 65535.0f + 0.5f); }
    }
    __syncthreads();
#pragma unroll
    for (int k = 0; k < 2; ++k) rend[k] = (int)s_cur[tid + k * NTHR];

    const float* imb = im0 + ((size_t)(b * CC) << 18);
    float* outb      = out + ((size_t)(b * CC) << 18);

    // ---- Phase 4: 8 channel-groups, register-staged pipeline ----
    float2 vimg[NREC];

    // preload group 0 into registers (latency hidden behind nothing to lose)
    {
        const float* p0c = imb;
        const float* p1c = imb + ((size_t)1 << 18);
#pragma unroll
        for (int r = 0; r < NREC; ++r) {
            const int i = tid + r * NTHR;
            if (i < NSRC) { vimg[r].x = p0c[rgi[r]]; vimg[r].y = p1c[rgi[r]]; }
        }
    }

    for (int g = 0; g < NGRP; ++g) {
        __syncthreads();   // previous gather done -> s_img reusable
#pragma unroll
        for (int r = 0; r < NREC; ++r) {
            const int i = tid + r * NTHR;
            if (i < NSRC) s_img[i] = vimg[r];
        }
        __syncthreads();   // s_img ready

        // issue next group's loads now; they complete under this group's gather
        if (g + 1 < NGRP) {
            const float* p0c = imb + ((size_t)((g + 1) * CB) << 18);
            const float* p1c = imb + ((size_t)((g + 1) * CB + 1) << 18);
#pragma unroll
            for (int r = 0; r < NREC; ++r) {
                const int i = tid + r * NTHR;
                if (i < NSRC) { vimg[r].x = p0c[rgi[r]]; vimg[r].y = p1c[rgi[r]]; }
            }
        }

        // gather: 2 dest pixels/thread, 2 channels in registers
#pragma unroll
        for (int k = 0; k < 2; ++k) {
            const int p   = tid + k * NTHR;
            const int beg = rbeg[k];
            const int end = rend[k];

            float a0 = 0.f, a1 = 0.f;
            for (int j = beg; j < end; ++j) {
                const unsigned e = s_ent[j];
                const int   sp = (int)(e >> 16);
                const float w  = (float)(e & 0xFFFFu) * (1.0f / 65535.0f);
                const float2 v = s_img[sp];
                a0 = fmaf(w, v.x, a0);
                a1 = fmaf(w, v.y, a1);
            }

            const int dy = p >> 5;
            const int dx = p & 31;
            float* op = outb + ((size_t)(g * CB) << 18) + ((h0 + dy) << 9) + (w0 + dx);
            op[0]               = a0;
            op[(size_t)1 << 18] = a1;
        }
    }
}

// Exact fallback for sources with flow outside [-RAD, RAD): global atomic
// scatter, stream-ordered AFTER fwarp_tile's non-atomic stores.
__global__ __launch_bounds__(256) void fwarp_fallback(
    const float* __restrict__ im0,
    const float* __restrict__ flow,
    float* __restrict__ out)
{
    const int t = blockIdx.x * blockDim.x + threadIdx.x;   // handles 4 pixels
    const int idx0 = t << 2;

    const float4 fA = ((const float4*)flow)[(t << 1)];
    const float4 fB = ((const float4*)flow)[(t << 1) + 1];
    const float pfx[4] = {fA.x, fA.z, fB.x, fB.z};
    const float pfy[4] = {fA.y, fA.w, fB.y, fB.w};

#pragma unroll
    for (int k = 0; k < 4; ++k) {
        const float fxv = pfx[k];
        const float fyv = pfy[k];
        const bool inrange = (fxv >= -(float)RAD) & (fxv < (float)RAD) &
                             (fyv >= -(float)RAD) & (fyv < (float)RAD);
        if (inrange) continue;  // handled by fwarp_tile

        const int idx = idx0 + k;
        const int w = idx & (WW - 1);
        const int h = (idx >> 9) & (HH - 1);
        const int b = idx >> 18;

        const float x = (float)w + fxv;
        const float y = (float)h + fyv;
        const float x0f = floorf(x);
        const float y0f = floorf(y);
        const int x0 = (int)x0f;
        const int y0 = (int)y0f;
        if (x0 < 0 || x0 > WW - 2 || y0 < 0 || y0 > HH - 2) continue;

        const float fx = x - x0f;
        const float fy = y - y0f;
        const float wnw = (1.0f - fx) * (1.0f - fy);
        const float wne = fx * (1.0f - fy);
        const float wsw = (1.0f - fx) * fy;
        const float wse = fx * fy;

        const size_t plane = (size_t)HH * WW;
        const float* srcb = im0 + (size_t)b * CC * plane + (size_t)h * WW + w;
        float* dstb       = out + (size_t)b * CC * plane;
        const int o = y0 * WW + x0;

#pragma unroll
        for (int c = 0; c < CC; ++c) {
            const float v = srcb[c * plane];
            float* dc = dstb + c * plane;
            atomicAdd(dc + o,          v * wnw);
            atomicAdd(dc + o + 1,      v * wne);
            atomicAdd(dc + o + WW,     v * wsw);
            atomicAdd(dc + o + WW + 1, v * wse);
        }
    }
}

extern "C" void kernel_launch(void* const* d_in, const int* in_sizes, int n_in,
                              void* d_out, int out_size, void* d_ws, size_t ws_size,
                              hipStream_t stream) {
    const float* im0  = (const float*)d_in[0];
    const float* flow = (const float*)d_in[1];
    float* out = (float*)d_out;

    // Main kernel writes every output element exactly once -> no memset needed.
    const int n_tiles = BB * (HH / TIL) * (WW / TIL);  // 2048
    fwarp_tile<<<n_tiles, NTHR, 0, stream>>>(im0, flow, out);

    // Rare long-range sources: exact global-atomic scatter, ordered after.
    const int n_pix = BB * HH * WW;                    // 2M; 4 px/thread
    fwarp_fallback<<<n_pix / (256 * 4), 256, 0, stream>>>(im0, flow, out);
}

// Round 5
// 326.415 us; speedup vs baseline: 2.8716x; 1.0017x over previous
//
#include <hip/hip_runtime.h>

// forward_warp bilinear scatter-add, v6: CB=4 CSR gather, fused two-cursor walk.
// im0: [B,C,H,W] fp32, flow: [B,H,W,2] fp32 (dx,dy), out: [B,C,H,W] fp32
// B=8, C=16, H=512, W=512
//
// v5 post-mortem: 97us, VALU 41% / LDS ~35% / HBM 27% -- cost is CSR re-walk
// (NGRP=8 passes x 2.6x divergence tax), not fma (2us of real work).
// v6: (1) CB=4 float4 s_img -> NGRP=4, halves entry-visits, 4 fma per visit;
//     (2) s_cur packed 2xu16/word (counts<=6400) -> LDS 53.3KB keeps 3 blk/CU;
//     (3) fused two-cursor gather: both pixels' rows walked in one predicated
//         loop -> wave rounds max(max(L0,L1)) ~12 vs 22;
//     (4) keep v5's register async-stage (T14) + XCD chunk swizzle (T1).

#define BB 8
#define CC 16
#define HH 512
#define WW 512
#define TIL 32             // dest tile edge
#define RAD 4              // halo radius; main path requires f in [-RAD, RAD)
#define REG (TIL + 2*RAD)  // 40
#define NSRC (REG*REG)     // 1600
#define NTHR 512
#define NREC ((NSRC + NTHR - 1) / NTHR)  // 4 records per thread (last partial)
#define NENT (NSRC * 4)    // hard bound on CSR entries: 6400 (fits u16)
#define CB 4               // channels per group (float4-interleaved LDS image)
#define NGRP (CC / CB)     // 4
#define NPIX (TIL * TIL)   // 1024

__global__ __launch_bounds__(NTHR, 6) void fwarp_tile(
    const float* __restrict__ im0,
    const float* __restrict__ flow,
    float* __restrict__ out)
{
    __shared__ unsigned s_ent[NENT];        // 25.6 KB  entry: spat<<16 | u16 w
    __shared__ unsigned s_cur[NPIX / 2];    // 2 KB     2 x u16 per word
    __shared__ float4   s_img[NSRC];        // 25.6 KB  4-channel-interleaved img
    __shared__ unsigned s_wtot[8];
    // total 53,280 B -> 3 blocks/CU (54,613 B budget)

    const int tid = threadIdx.x;
    // XCD chunk swizzle: 2048 blocks = 8 XCDs x 256; XCD k owns batch b=k.
    const int bid  = blockIdx.x;
    const int tile = ((bid & 7) << 8) | (bid >> 3);
    const int tcx = tile & 15;
    const int tcy = (tile >> 4) & 15;
    const int b   = tile >> 8;
    const int w0  = tcx * TIL;
    const int h0  = tcy * TIL;

    const float2* flow2 = (const float2*)flow + ((size_t)b << 18);

    // ---- Phase A: decode each source ONCE into registers ----
    float4 rw[NREC];       // corner weights (nw, ne, sw, se)
    int    rp0[NREC];      // ly*TIL + lx (NW corner pixel index, may be <0)
    int    rk[NREC];       // corner validity mask
    int    rgi[NREC];      // global spatial index for staging (0 if OOB)

    for (int j = tid; j < NPIX / 2; j += NTHR) s_cur[j] = 0u;

#pragma unroll
    for (int r = 0; r < NREC; ++r) {
        rk[r] = 0; rp0[r] = 0; rgi[r] = 0;
        rw[r] = make_float4(0.f, 0.f, 0.f, 0.f);
        const int i = tid + r * NTHR;
        if (i < NSRC) {
            const int ry = i / REG;
            const int rx = i - ry * REG;
            const int sy = h0 - RAD + ry;
            const int sx = w0 - RAD + rx;
            const bool inimg = (sx >= 0) & (sx < WW) & (sy >= 0) & (sy < HH);
            rgi[r] = inimg ? ((sy << 9) + sx) : 0;

            float fxv = 0.0f, fyv = 0.0f;
            if (inimg) {
                const float2 f = flow2[(sy << 9) + sx];
                fxv = f.x; fyv = f.y;
            }
            const float x = (float)sx + fxv;
            const float y = (float)sy + fyv;
            const float x0f = floorf(x);
            const float y0f = floorf(y);
            const int x0 = (int)x0f;
            const int y0 = (int)y0f;

            const bool inrange = (fxv >= -(float)RAD) & (fxv < (float)RAD) &
                                 (fyv >= -(float)RAD) & (fyv < (float)RAD);
            const bool valid = inimg && inrange &&
                               (x0 >= 0) && (x0 <= WW - 2) && (y0 >= 0) && (y0 <= HH - 2);

            const float fx = x - x0f;
            const float fy = y - y0f;
            const int lx = x0 - w0;
            const int ly = y0 - h0;

            const bool okW = (lx >= 0)  & (lx < TIL);
            const bool okE = (lx >= -1) & (lx < TIL - 1);
            const bool okN = (ly >= 0)  & (ly < TIL);
            const bool okS = (ly >= -1) & (ly < TIL - 1);

            const float wnw = (1.0f - fx) * (1.0f - fy);
            const float wne = fx * (1.0f - fy);
            const float wsw = (1.0f - fx) * fy;
            const float wse = fx * fy;

            int m = 0;
            if (valid && okN && okW && (wnw != 0.0f)) m |= 1;
            if (valid && okN && okE && (wne != 0.0f)) m |= 2;
            if (valid && okS && okW && (wsw != 0.0f)) m |= 4;
            if (valid && okS && okE && (wse != 0.0f)) m |= 8;

            rk[r]  = m;
            rp0[r] = ly * TIL + lx;
            rw[r]  = make_float4(wnw, wne, wsw, wse);
        }
    }
    __syncthreads();

    // ---- Phase 1: count contributions per dest pixel (packed u16 halves) ----
#pragma unroll
    for (int r = 0; r < NREC; ++r) {
        const int m = rk[r];
        const int p0 = rp0[r];
        if (m & 1) { const int p = p0;           atomicAdd(&s_cur[p >> 1], 1u << ((p & 1) * 16)); }
        if (m & 2) { const int p = p0 + 1;       atomicAdd(&s_cur[p >> 1], 1u << ((p & 1) * 16)); }
        if (m & 4) { const int p = p0 + TIL;     atomicAdd(&s_cur[p >> 1], 1u << ((p & 1) * 16)); }
        if (m & 8) { const int p = p0 + TIL + 1; atomicAdd(&s_cur[p >> 1], 1u << ((p & 1) * 16)); }
    }
    __syncthreads();

    // ---- Phase 2: exclusive prefix scan over 1024 counts (1 word/thread) ----
    {
        const int lane = tid & 63;
        const int wv   = tid >> 6;             // 0..7
        const unsigned word = s_cur[tid];
        const unsigned clo = word & 0xFFFFu;
        const unsigned chi = word >> 16;
        const unsigned mysum = clo + chi;
        unsigned inc = mysum;
#pragma unroll
        for (int d = 1; d < 64; d <<= 1) {
            const unsigned u = __shfl_up(inc, d);
            if (lane >= d) inc += u;
        }
        if (lane == 63) s_wtot[wv] = inc;
        __syncthreads();
        unsigned wpre = 0;
#pragma unroll
        for (int w = 0; w < 7; ++w) if (wv > w) wpre += s_wtot[w];
        const unsigned olo = wpre + inc - mysum;
        const unsigned ohi = olo + clo;
        s_cur[tid] = olo | (ohi << 16);        // packed row starts / cursors
    }
    __syncthreads();

    // capture row starts for our gather pixels BEFORE cursors get bumped
    int rbeg[2], rend[2];
#pragma unroll
    for (int k = 0; k < 2; ++k) {
        const int p = tid + k * NTHR;
        rbeg[k] = (int)((s_cur[p >> 1] >> ((p & 1) * 16)) & 0xFFFFu);
    }
    __syncthreads();

    // ---- Phase 3: fill CSR entries (spat<<16 | u16 fixed-point weight) ----
#pragma unroll
    for (int r = 0; r < NREC; ++r) {
        const int i = tid + r * NTHR;          // source spat (local index)
        const int m = rk[r];
        const int p0 = rp0[r];
        const float4 w4 = rw[r];
        if (m & 1) { const int p = p0;
            const unsigned old = atomicAdd(&s_cur[p >> 1], 1u << ((p & 1) * 16));
            const unsigned s = (old >> ((p & 1) * 16)) & 0xFFFFu;
            s_ent[s] = ((unsigned)i << 16) | (unsigned)(w4.x * 65535.0f + 0.5f); }
        if (m & 2) { const int p = p0 + 1;
            const unsigned old = atomicAdd(&s_cur[p >> 1], 1u << ((p & 1) * 16));
            const unsigned s = (old >> ((p & 1) * 16)) & 0xFFFFu;
            s_ent[s] = ((unsigned)i << 16) | (unsigned)(w4.y * 65535.0f + 0.5f); }
        if (m & 4) { const int p = p0 + TIL;
            const unsigned old = atomicAdd(&s_cur[p >> 1], 1u << ((p & 1) * 16));
            const unsigned s = (old >> ((p & 1) * 16)) & 0xFFFFu;
            s_ent[s] = ((unsigned)i << 16) | (unsigned)(w4.z * 65535.0f + 0.5f); }
        if (m & 8) { const int p = p0 + TIL + 1;
            const unsigned old = atomicAdd(&s_cur[p >> 1], 1u << ((p & 1) * 16));
            const unsigned s = (old >> ((p & 1) * 16)) & 0xFFFFu;
            s_ent[s] = ((unsigned)i << 16) | (unsigned)(w4.w * 65535.0f + 0.5f); }
    }
    __syncthreads();
#pragma unroll
    for (int k = 0; k < 2; ++k) {
        const int p = tid + k * NTHR;
        rend[k] = (int)((s_cur[p >> 1] >> ((p & 1) * 16)) & 0xFFFFu);
    }

    const float* imb = im0 + ((size_t)(b * CC) << 18);
    float* outb      = out + ((size_t)(b * CC) << 18);

    // ---- Phase 4: 4 channel-groups, register-staged pipeline ----
    float4 vimg[NREC];

    // preload group 0 into registers
    {
        const float* c0 = imb;
#pragma unroll
        for (int r = 0; r < NREC; ++r) {
            const int i = tid + r * NTHR;
            if (i < NSRC) {
                vimg[r].x = c0[rgi[r]];
                vimg[r].y = c0[((size_t)1 << 18) + rgi[r]];
                vimg[r].z = c0[((size_t)2 << 18) + rgi[r]];
                vimg[r].w = c0[((size_t)3 << 18) + rgi[r]];
            }
        }
    }

    for (int g = 0; g < NGRP; ++g) {
        __syncthreads();   // previous gather done -> s_img reusable
#pragma unroll
        for (int r = 0; r < NREC; ++r) {
            const int i = tid + r * NTHR;
            if (i < NSRC) s_img[i] = vimg[r];
        }
        __syncthreads();   // s_img ready

        // issue next group's loads now; they complete under this group's gather
        if (g + 1 < NGRP) {
            const float* c0 = imb + ((size_t)((g + 1) * CB) << 18);
#pragma unroll
            for (int r = 0; r < NREC; ++r) {
                const int i = tid + r * NTHR;
                if (i < NSRC) {
                    vimg[r].x = c0[rgi[r]];
                    vimg[r].y = c0[((size_t)1 << 18) + rgi[r]];
                    vimg[r].z = c0[((size_t)2 << 18) + rgi[r]];
                    vimg[r].w = c0[((size_t)3 << 18) + rgi[r]];
                }
            }
        }

        // fused two-cursor gather: both pixels advance per round
        int j0 = rbeg[0], j1 = rbeg[1];
        const int e0 = rend[0], e1 = rend[1];
        float4 a0 = make_float4(0.f, 0.f, 0.f, 0.f);
        float4 a1 = make_float4(0.f, 0.f, 0.f, 0.f);
        while ((j0 < e0) | (j1 < e1)) {
            if (j0 < e0) {
                const unsigned e = s_ent[j0++];
                const float w  = (float)(e & 0xFFFFu) * (1.0f / 65535.0f);
                const float4 v = s_img[e >> 16];
                a0.x = fmaf(w, v.x, a0.x);
                a0.y = fmaf(w, v.y, a0.y);
                a0.z = fmaf(w, v.z, a0.z);
                a0.w = fmaf(w, v.w, a0.w);
            }
            if (j1 < e1) {
                const unsigned e = s_ent[j1++];
                const float w  = (float)(e & 0xFFFFu) * (1.0f / 65535.0f);
                const float4 v = s_img[e >> 16];
                a1.x = fmaf(w, v.x, a1.x);
                a1.y = fmaf(w, v.y, a1.y);
                a1.z = fmaf(w, v.z, a1.z);
                a1.w = fmaf(w, v.w, a1.w);
            }
        }

        // coalesced per-plane stores
        {
            const int p  = tid;
            const int dy = p >> 5;
            const int dx = p & 31;
            float* op = outb + ((size_t)(g * CB) << 18) + ((h0 + dy) << 9) + (w0 + dx);
            op[0]               = a0.x;
            op[(size_t)1 << 18] = a0.y;
            op[(size_t)2 << 18] = a0.z;
            op[(size_t)3 << 18] = a0.w;
        }
        {
            const int p  = tid + NTHR;
            const int dy = p >> 5;
            const int dx = p & 31;
            float* op = outb + ((size_t)(g * CB) << 18) + ((h0 + dy) << 9) + (w0 + dx);
            op[0]               = a1.x;
            op[(size_t)1 << 18] = a1.y;
            op[(size_t)2 << 18] = a1.z;
            op[(size_t)3 << 18] = a1.w;
        }
    }
}

// Exact fallback for sources with flow outside [-RAD, RAD): global atomic
// scatter, stream-ordered AFTER fwarp_tile's non-atomic stores.
__global__ __launch_bounds__(256) void fwarp_fallback(
    const float* __restrict__ im0,
    const float* __restrict__ flow,
    float* __restrict__ out)
{
    const int t = blockIdx.x * blockDim.x + threadIdx.x;   // handles 4 pixels
    const int idx0 = t << 2;

    const float4 fA = ((const float4*)flow)[(t << 1)];
    const float4 fB = ((const float4*)flow)[(t << 1) + 1];
    const float pfx[4] = {fA.x, fA.z, fB.x, fB.z};
    const float pfy[4] = {fA.y, fA.w, fB.y, fB.w};

#pragma unroll
    for (int k = 0; k < 4; ++k) {
        const float fxv = pfx[k];
        const float fyv = pfy[k];
        const bool inrange = (fxv >= -(float)RAD) & (fxv < (float)RAD) &
                             (fyv >= -(float)RAD) & (fyv < (float)RAD);
        if (inrange) continue;  // handled by fwarp_tile

        const int idx = idx0 + k;
        const int w = idx & (WW - 1);
        const int h = (idx >> 9) & (HH - 1);
        const int b = idx >> 18;

        const float x = (float)w + fxv;
        const float y = (float)h + fyv;
        const float x0f = floorf(x);
        const float y0f = floorf(y);
        const int x0 = (int)x0f;
        const int y0 = (int)y0f;
        if (x0 < 0 || x0 > WW - 2 || y0 < 0 || y0 > HH - 2) continue;

        const float fx = x - x0f;
        const float fy = y - y0f;
        const float wnw = (1.0f - fx) * (1.0f - fy);
        const float wne = fx * (1.0f - fy);
        const float wsw = (1.0f - fx) * fy;
        const float wse = fx * fy;

        const size_t plane = (size_t)HH * WW;
        const float* srcb = im0 + (size_t)b * CC * plane + (size_t)h * WW + w;
        float* dstb       = out + (size_t)b * CC * plane;
        const int o = y0 * WW + x0;

#pragma unroll
        for (int c = 0; c < CC; ++c) {
            const float v = srcb[c * plane];
            float* dc = dstb + c * plane;
            atomicAdd(dc + o,          v * wnw);
            atomicAdd(dc + o + 1,      v * wne);
            atomicAdd(dc + o + WW,     v * wsw);
            atomicAdd(dc + o + WW + 1, v * wse);
        }
    }
}

extern "C" void kernel_launch(void* const* d_in, const int* in_sizes, int n_in,
                              void* d_out, int out_size, void* d_ws, size_t ws_size,
                              hipStream_t stream) {
    const float* im0  = (const float*)d_in[0];
    const float* flow = (const float*)d_in[1];
    float* out = (float*)d_out;

    // Main kernel writes every output element exactly once -> no memset needed.
    const int n_tiles = BB * (HH / TIL) * (WW / TIL);  // 2048
    fwarp_tile<<<n_tiles, NTHR, 0, stream>>>(im0, flow, out);

    // Rare long-range sources: exact global-atomic scatter, ordered after.
    const int n_pix = BB * HH * WW;                    // 2M; 4 px/thread
    fwarp_fallback<<<n_pix / (256 * 4), 256, 0, stream>>>(im0, flow, out);
}